// Round 9
// baseline (98.114 us; speedup 1.0000x reference)
//
#include <hip/hip_runtime.h>
#include <hip/hip_bf16.h>

#define EPSW 1e-6f

typedef __attribute__((ext_vector_type(4))) float floatx4;
typedef __attribute__((ext_vector_type(8))) short shortx8;   // 8 bf16 (4 VGPRs)

// round-to-nearest-even float -> bf16 bits (finite inputs)
__device__ __forceinline__ unsigned short f2bf(float f) {
    unsigned int u = __float_as_uint(f);
    u = (u + 0x7fffu + ((u >> 16) & 1u)) >> 16;
    return (unsigned short)u;
}

// pack 8 fp32 -> 8 bf16 (round-half-up: +0x8000, hi16 via v_perm).
// <=0.5 ulp vs RNE; absmax-validated rounds 3/5/7/8.
__device__ __forceinline__ shortx8 pack8(floatx4 a, floatx4 b) {
    union { shortx8 v; unsigned int u[4]; } r;
    const unsigned a0 = __float_as_uint(a.x) + 0x8000u, a1 = __float_as_uint(a.y) + 0x8000u;
    const unsigned a2 = __float_as_uint(a.z) + 0x8000u, a3 = __float_as_uint(a.w) + 0x8000u;
    const unsigned b0 = __float_as_uint(b.x) + 0x8000u, b1 = __float_as_uint(b.y) + 0x8000u;
    const unsigned b2 = __float_as_uint(b.z) + 0x8000u, b3 = __float_as_uint(b.w) + 0x8000u;
    r.u[0] = __builtin_amdgcn_perm(a1, a0, 0x07060302u);
    r.u[1] = __builtin_amdgcn_perm(a3, a2, 0x07060302u);
    r.u[2] = __builtin_amdgcn_perm(b1, b0, 0x07060302u);
    r.u[3] = __builtin_amdgcn_perm(b3, b2, 0x07060302u);
    return r.v;
}

// ---------------------------------------------------------------------------
// prep: 32 blocks x 256 threads (round-8 validated, unchanged).
//   blocks 0..15 : W (128 x 2000 fp32) -> wt bf16, MFMA B-fragment layout
//                  [kg][h][8], kg = k/8, K padded to 2048.
//   blocks 16..31: each redundantly builds A (4096 edge-ops, LDS) + one
//                  4-column slice of Mt[c][n] = (A@A)[n][c].
// ---------------------------------------------------------------------------
__global__ __launch_bounds__(256) void prep(const float* __restrict__ W,
                                            const int* __restrict__ ei,
                                            const float* __restrict__ ew,
                                            unsigned short* __restrict__ wt,
                                            float* __restrict__ Mt) {
    const int bid = blockIdx.x;
    const int t   = threadIdx.x;
    if (bid < 16) {
#pragma unroll
        for (int i = 0; i < 8; ++i) {
            const int G  = bid * 2048 + i * 256 + t;  // 0..32767
            const int kg = G >> 7;
            const int h  = G & 127;
            const int k  = kg * 8;
            floatx4 v0 = (floatx4){0.f, 0.f, 0.f, 0.f};
            floatx4 v1 = (floatx4){0.f, 0.f, 0.f, 0.f};
            if (k < 2000) {  // kg<=249 -> whole granule valid
                v0 = *(const floatx4*)(W + (size_t)h * 2000 + k);
                v1 = *(const floatx4*)(W + (size_t)h * 2000 + k + 4);
            }
            unsigned short* p = wt + ((size_t)kg * 128 + h) * 8;
            p[0] = f2bf(v0.x); p[1] = f2bf(v0.y); p[2] = f2bf(v0.z); p[3] = f2bf(v0.w);
            p[4] = f2bf(v1.x); p[5] = f2bf(v1.y); p[6] = f2bf(v1.z); p[7] = f2bf(v1.w);
        }
    } else {
        __shared__ float A[4096];
        __shared__ float deg[64];
        __shared__ float dinv[64];
        if (t < 64) deg[t] = 1.0f;             // self-loop pre-added
        for (int i = t; i < 4096; i += 256) A[i] = 0.0f;
        __syncthreads();
        const int* srcp = ei;
        const int* dstp = ei + 4096;
#pragma unroll
        for (int i = 0; i < 16; ++i) {
            const int e = i * 256 + t;
            float w = ew[e];
            w = (w <= 0.0f) ? EPSW : w;
            atomicAdd(&deg[dstp[e]], w);
        }
        __syncthreads();
        if (t < 64) dinv[t] = 1.0f / sqrtf(deg[t]);
        __syncthreads();
#pragma unroll
        for (int i = 0; i < 16; ++i) {
            const int e = i * 256 + t;
            float w = ew[e];
            w = (w <= 0.0f) ? EPSW : w;
            const int s = srcp[e], d = dstp[e];
            atomicAdd(&A[d * 64 + s], dinv[s] * w * dinv[d]);
        }
        if (t < 64) atomicAdd(&A[t * 64 + t], dinv[t] * dinv[t]);
        __syncthreads();
        const int c = (bid - 16) * 4 + (t >> 6);
        const int n = t & 63;
        float s = 0.0f;
#pragma unroll 8
        for (int k = 0; k < 64; ++k) s += A[n * 64 + k] * A[k * 64 + c];
        Mt[c * 64 + n] = s;
    }
}

// ---------------------------------------------------------------------------
// gemm_apply: 256 blocks x 1024 threads (16 waves = 4 waves/SIMD for latency
// hiding). Block bid = ht*32 + b (bid%8 == b%8 -> XCD round-robin pins 4
// batches/XCD for x L2 reuse). Wave (rt 0..3, kh 0..3): 16x16 tile, K-quarter
// kh*512 -> only 16 serial k-steps/wave (vs 32 in round 8). Per step: a-frag
// = 2 coalesced float4 from fp32 x + inline pack8; b-frag = 16B from
// pre-baked wt. No LDS, no barriers in the main loop.
// Epilogue: Ms staged at kernel start; 4 kh-partials reduced via zs[64][17]
// (3 barrier rounds); y = M.z + bias, 1 output/thread.
// ---------------------------------------------------------------------------
__global__ __launch_bounds__(1024) void gemm_apply(
        const float* __restrict__ x,
        const unsigned short* __restrict__ wt,
        const float* __restrict__ Mt,
        const float* __restrict__ bias,
        float* __restrict__ y) {
    __shared__ float Ms[4096];        // Ms[m*64+n] = M[n][m]
    __shared__ float zs[64][17];
    const int t    = threadIdx.x;
    const int bid  = blockIdx.x;
    const int b    = bid & 31;
    const int ht   = bid >> 5;
    const int wave = t >> 6, lane = t & 63;
    const int m = lane & 15, q = lane >> 4;
    const int rt = wave & 3, kh = wave >> 2;   // kh 0..3

    // stage Ms (1024 float4 = whole 16 KB; latency hidden under MFMA loop)
    ((floatx4*)Ms)[t] = ((const floatx4*)Mt)[t];

    const float* xrow = x + (size_t)(b * 64 + rt * 16 + m) * 2000;
    const int kbase = kh * 512 + q * 8;
    const shortx8* Bg = (const shortx8*)wt;
    const int gb = (kh * 64 + q) * 128 + ht * 16 + m;    // +512 per step

    const floatx4 zero4 = (floatx4){0.f, 0.f, 0.f, 0.f};
    floatx4 acc0 = zero4, acc1 = zero4;
#pragma unroll 4
    for (int s = 0; s < 16; ++s) {
        const int k0 = kbase + s * 32;
        floatx4 f0 = zero4, f1 = zero4;
        if (k0 < 2000) {               // k0 % 8 == 0 -> k0 < 2000 => k0+8 <= 2000
            f0 = *(const floatx4*)(xrow + k0);
            f1 = *(const floatx4*)(xrow + k0 + 4);
        }
        const shortx8 af = pack8(f0, f1);
        const shortx8 bf = Bg[gb + s * 512];
        if (s & 1) acc1 = __builtin_amdgcn_mfma_f32_16x16x32_bf16(af, bf, acc1, 0, 0, 0);
        else       acc0 = __builtin_amdgcn_mfma_f32_16x16x32_bf16(af, bf, acc0, 0, 0, 0);
    }
    acc0 += acc1;

    // ===== 4-way kh-reduce via LDS (C/D layout: row = q*4+v, col = m) =====
    if (kh == 0) {
#pragma unroll
        for (int v = 0; v < 4; ++v) zs[rt * 16 + q * 4 + v][m] = acc0[v];
    }
    __syncthreads();
    if (kh == 1) {
#pragma unroll
        for (int v = 0; v < 4; ++v) zs[rt * 16 + q * 4 + v][m] += acc0[v];
    }
    __syncthreads();
    if (kh == 2) {
#pragma unroll
        for (int v = 0; v < 4; ++v) zs[rt * 16 + q * 4 + v][m] += acc0[v];
    }
    __syncthreads();
    if (kh == 3) {
#pragma unroll
        for (int v = 0; v < 4; ++v) zs[rt * 16 + q * 4 + v][m] += acc0[v];
    }
    __syncthreads();

    // ===== apply M + bias: 1024 outputs, 1/thread =====
    {
        const int n = t >> 4;         // 0..63
        const int h = t & 15;
        float s = bias[ht * 16 + h];
#pragma unroll
        for (int mm = 0; mm < 64; ++mm)
            s += Ms[mm * 64 + n] * zs[mm][h];   // 4-bank broadcast / 16-bank bcast
        y[(size_t)b * 8192 + (size_t)n * 128 + ht * 16 + h] = s;
    }
}

extern "C" void kernel_launch(void* const* d_in, const int* in_sizes, int n_in,
                              void* d_out, int out_size, void* d_ws, size_t ws_size,
                              hipStream_t stream) {
    const float* x    = (const float*)d_in[0];   // (2048, 2000) fp32
    const int*   ei   = (const int*)d_in[1];     // (2, 4096)
    const float* ew   = (const float*)d_in[2];   // (4096,)
    const float* W    = (const float*)d_in[3];   // (128, 2000) fp32
    const float* bias = (const float*)d_in[4];   // (128,)
    float* y = (float*)d_out;                    // (32, 64, 128) fp32

    float* Mt = (float*)d_ws;                            // 4096 f
    unsigned short* wt = (unsigned short*)(Mt + 4096);   // 256*128*8 bf16 (512 KB)

    prep<<<32, 256, 0, stream>>>(W, ei, ew, wt, Mt);
    gemm_apply<<<256, 1024, 0, stream>>>(x, wt, Mt, bias, y);
}